// Round 5
// baseline (229.166 us; speedup 1.0000x reference)
//
#include <hip/hip_runtime.h>
#include <hip/hip_bf16.h>

typedef __attribute__((ext_vector_type(8))) short short8;
typedef __attribute__((ext_vector_type(4))) short short4v;
typedef __attribute__((ext_vector_type(4))) float floatx4;

__device__ __forceinline__ unsigned short f2b(float f) {
  unsigned int v;
  __builtin_memcpy(&v, &f, 4);
  unsigned int r = (v + 0x7FFFu + ((v >> 16) & 1u)) >> 16;
  return (unsigned short)r;
}

// pack two fp32 -> bf16x2 (low = a, high = b)
__device__ __forceinline__ unsigned int f2b_pk(float a, float b) {
#if __has_builtin(__builtin_amdgcn_cvt_pk_bf16_f32)
  typedef __attribute__((ext_vector_type(2))) __bf16 bf16x2;
  bf16x2 r = __builtin_amdgcn_cvt_pk_bf16_f32(a, b);
  unsigned int u;
  __builtin_memcpy(&u, &r, 4);
  return u;
#else
  return ((unsigned int)f2b(b) << 16) | (unsigned int)f2b(a);
#endif
}

__device__ __forceinline__ float fast_exp2(float x) {
#if __has_builtin(__builtin_amdgcn_exp2f)
  return __builtin_amdgcn_exp2f(x);
#else
  return __builtin_exp2f(x);
#endif
}

__device__ __forceinline__ void async_copy16(const void* g, void* l) {
  __builtin_amdgcn_global_load_lds(
      (const __attribute__((address_space(1))) unsigned int*)g,
      (__attribute__((address_space(3))) unsigned int*)l, 16, 0, 0);
}

// 0.125 (1/sqrt(dk)) * log2(e): folded into Q so attention uses exp2 directly.
#define QSCALE 0.18033688011112042f

// One launch converts x (1M float4 groups) + 4 weight matrices (256K groups each).
__global__ __launch_bounds__(256) void cvt_all_kernel(
    const float* __restrict__ x,
    const float* __restrict__ w0, const float* __restrict__ w1,
    const float* __restrict__ w2, const float* __restrict__ w3,
    unsigned short* __restrict__ xb,
    unsigned short* __restrict__ d0, unsigned short* __restrict__ d1,
    unsigned short* __restrict__ d2, unsigned short* __restrict__ d3)
{
  int gid = blockIdx.x * 256 + threadIdx.x;
  const float* src;
  unsigned short* dst;
  size_t off;
  if (gid < (1 << 20)) {
    src = x; dst = xb; off = gid;
  } else {
    int g = gid - (1 << 20);
    int w = g >> 18;
    off = g & 0x3FFFF;
    src = (w == 0) ? w0 : (w == 1) ? w1 : (w == 2) ? w2 : w3;
    dst = (w == 0) ? d0 : (w == 1) ? d1 : (w == 2) ? d2 : d3;
  }
  floatx4 v = *(const floatx4*)(src + off * 4);
  unsigned int lo = f2b_pk(v[0], v[1]), hi = f2b_pk(v[2], v[3]);
  unsigned long long r = ((unsigned long long)hi << 32) | lo;
  *(unsigned long long*)(dst + off * 4) = r;
}

// QKV GEMM: C = A @ W^T + bias, 128x128 tile, BK=32. z=0: Q (pre-scaled by
// QSCALE), z=1: K, z=2: V written transposed as VT[bh][d][t].
__global__ __launch_bounds__(256) void gemm_qkv_kernel(
    const unsigned short* __restrict__ A,
    const unsigned short* __restrict__ W0, const unsigned short* __restrict__ W1,
    const unsigned short* __restrict__ W2,
    const float* __restrict__ bias0, const float* __restrict__ bias1,
    const float* __restrict__ bias2,
    unsigned short* __restrict__ Qo, unsigned short* __restrict__ Ko,
    unsigned short* __restrict__ VTo)
{
  const int z = blockIdx.z;
  const unsigned short* W  = (z == 0) ? W0 : (z == 1) ? W1 : W2;
  const float* bias        = (z == 0) ? bias0 : (z == 1) ? bias1 : bias2;

  __shared__ alignas(16) unsigned short sA[128 * 32];
  __shared__ alignas(16) unsigned short sB[128 * 32];

  const int tid  = threadIdx.x;
  const int lane = tid & 63;
  const int wave = tid >> 6;
  const int col  = lane & 15;
  const int quad = lane >> 4;
  const int wm   = (wave >> 1) * 64;
  const int wn   = (wave & 1) * 64;
  const int m0   = blockIdx.y * 128;
  const int n0   = blockIdx.x * 128;

  floatx4 acc[4][4];
#pragma unroll
  for (int i = 0; i < 4; ++i)
#pragma unroll
    for (int j = 0; j < 4; ++j) acc[i][j] = (floatx4){0.f, 0.f, 0.f, 0.f};

  for (int k0 = 0; k0 < 1024; k0 += 32) {
    __syncthreads();
#pragma unroll
    for (int i = 0; i < 2; ++i) {
      int c   = i * 256 + tid;
      int row = c >> 2;
      int ko  = (c & 3) * 8;
      async_copy16(A + (size_t)(m0 + row) * 1024 + k0 + ko, sA + c * 8);
      async_copy16(W + (size_t)(n0 + row) * 1024 + k0 + ko, sB + c * 8);
    }
    __syncthreads();
    short8 af[4], bf[4];
#pragma unroll
    for (int mi = 0; mi < 4; ++mi)
      af[mi] = *(const short8*)(sA + (wm + mi * 16 + col) * 32 + quad * 8);
#pragma unroll
    for (int ni = 0; ni < 4; ++ni)
      bf[ni] = *(const short8*)(sB + (wn + ni * 16 + col) * 32 + quad * 8);
#pragma unroll
    for (int mi = 0; mi < 4; ++mi)
#pragma unroll
      for (int ni = 0; ni < 4; ++ni)
        acc[mi][ni] = __builtin_amdgcn_mfma_f32_16x16x32_bf16(af[mi], bf[ni], acc[mi][ni], 0, 0, 0);
  }

#pragma unroll
  for (int ni = 0; ni < 4; ++ni) {
    int n = n0 + wn + ni * 16 + col;
    float bv = bias[n];
#pragma unroll
    for (int mi = 0; mi < 4; ++mi) {
      int mbase = m0 + wm + mi * 16 + quad * 4;
#pragma unroll
      for (int r = 0; r < 4; ++r) {
        int m = mbase + r;
        float val = acc[mi][ni][r] + bv;
        if (z == 0) {
          Qo[(size_t)m * 1024 + n] = f2b(val * QSCALE);
        } else if (z == 1) {
          Ko[(size_t)m * 1024 + n] = f2b(val);
        } else {
          int d = n & 63, h = n >> 6;
          int bb = m >> 11, t = m & 2047;
          VTo[(((size_t)bb * 16 + h) * 64 + d) * 2048 + t] = f2b(val);
        }
      }
    }
  }
}

// Out-proj GEMM: 128(M)x64(N) tile for occupancy at N=1024; fp32 output.
__global__ __launch_bounds__(256) void gemm_out_kernel(
    const unsigned short* __restrict__ A, const unsigned short* __restrict__ W,
    const float* __restrict__ bias, float* __restrict__ DF)
{
  __shared__ alignas(16) unsigned short sA[128 * 32];
  __shared__ alignas(16) unsigned short sB[64 * 32];

  const int tid  = threadIdx.x;
  const int lane = tid & 63;
  const int wave = tid >> 6;
  const int col  = lane & 15;
  const int quad = lane >> 4;
  const int wm   = (wave >> 1) * 64;
  const int wn   = (wave & 1) * 32;
  const int m0   = blockIdx.y * 128;
  const int n0   = blockIdx.x * 64;

  floatx4 acc[4][2];
#pragma unroll
  for (int i = 0; i < 4; ++i)
#pragma unroll
    for (int j = 0; j < 2; ++j) acc[i][j] = (floatx4){0.f, 0.f, 0.f, 0.f};

  for (int k0 = 0; k0 < 1024; k0 += 32) {
    __syncthreads();
#pragma unroll
    for (int i = 0; i < 2; ++i) {
      int c   = i * 256 + tid;
      int row = c >> 2;
      int ko  = (c & 3) * 8;
      async_copy16(A + (size_t)(m0 + row) * 1024 + k0 + ko, sA + c * 8);
    }
    {
      int row = tid >> 2;
      int ko  = (tid & 3) * 8;
      async_copy16(W + (size_t)(n0 + row) * 1024 + k0 + ko, sB + tid * 8);
    }
    __syncthreads();
    short8 af[4], bf[2];
#pragma unroll
    for (int mi = 0; mi < 4; ++mi)
      af[mi] = *(const short8*)(sA + (wm + mi * 16 + col) * 32 + quad * 8);
#pragma unroll
    for (int ni = 0; ni < 2; ++ni)
      bf[ni] = *(const short8*)(sB + (wn + ni * 16 + col) * 32 + quad * 8);
#pragma unroll
    for (int mi = 0; mi < 4; ++mi)
#pragma unroll
      for (int ni = 0; ni < 2; ++ni)
        acc[mi][ni] = __builtin_amdgcn_mfma_f32_16x16x32_bf16(af[mi], bf[ni], acc[mi][ni], 0, 0, 0);
  }

#pragma unroll
  for (int ni = 0; ni < 2; ++ni) {
    int n = n0 + wn + ni * 16 + col;
    float bv = bias[n];
#pragma unroll
    for (int mi = 0; mi < 4; ++mi) {
      int mbase = m0 + wm + mi * 16 + quad * 4;
#pragma unroll
      for (int r = 0; r < 4; ++r)
        DF[(size_t)(mbase + r) * 1024 + n] = acc[mi][ni][r] + bv;
    }
  }
}

// Flash attention v3: barrier-free pipelined K-loop. Block = (bh, 64 q-rows),
// 4 waves; wave w owns k-slice [w*32, w*32+32) of each 128-k tile. Q frags in
// registers. All LDS slices wave-private; ordering via s_waitcnt vmcnt(N):
//   issue K(t+1) -> vm(8)=K(t) ready -> QK/exp/P -> vm(4)=V(t) ready ->
//   vf reads -> lgkm(0) -> issue V(t+1) -> PV.
// Partial O (per-wave k-slice) reduced once at the end via LDS.
__global__ __launch_bounds__(256) void attention_kernel(
    const unsigned short* __restrict__ Q, const unsigned short* __restrict__ K,
    const unsigned short* __restrict__ VT, unsigned short* __restrict__ CTX)
{
  __shared__ alignas(16) unsigned short sKb[16384]; // [2 buf][4 w][2 slab][32 k][32 dk]
  __shared__ alignas(16) unsigned short sVb[8192];  // [4 w][64 d][32 k]
  __shared__ alignas(16) unsigned short sPb[9216];  // [4 w][64 q][36]; prologue: Q [2 slab][64 q][32]
  __shared__ float sL[4][64];

  const int bh = blockIdx.x;
  const int b = bh >> 4, h = bh & 15;
  const int q0 = blockIdx.y * 64;
  const int tid  = threadIdx.x;
  const int lane = tid & 63;
  const int wave = tid >> 6;
  const int col  = lane & 15;
  const int quad = lane >> 4;
  const int l4   = lane >> 2;       // 0..15
  const int lo4  = (lane & 3) * 8;  // sub-offset in shorts

  const unsigned short* Kg = K + (size_t)(b * 2048) * 1024 + h * 64;
  const unsigned short* Vg = VT + (size_t)bh * 64 * 2048;

  // ---- prologue: stage Q into sPb as [slab][64 q][32]; issue K(0), V(0)
#pragma unroll
  for (int s = 0; s < 2; ++s)
    async_copy16(Q + (size_t)(b * 2048 + q0 + wave * 16 + l4) * 1024 + h * 64 + s * 32 + lo4,
                 sPb + s * 2048 + wave * 512 + lane * 8);
  {
    unsigned short* kd = sKb + wave * 2048;
#pragma unroll
    for (int s = 0; s < 2; ++s)
#pragma unroll
      for (int j = 0; j < 2; ++j)
        async_copy16(Kg + (size_t)(wave * 32 + j * 16 + l4) * 1024 + s * 32 + lo4,
                     kd + s * 1024 + j * 512 + lane * 8);
    unsigned short* vd = sVb + wave * 2048;
#pragma unroll
    for (int i = 0; i < 4; ++i)
      async_copy16(Vg + (size_t)(i * 16 + l4) * 2048 + wave * 32 + lo4,
                   vd + i * 512 + lane * 8);
  }
  __builtin_amdgcn_s_waitcnt(0xF70);  // vmcnt(0): Q/K0/V0 staged (prologue only)
  __syncthreads();

  short8 qf[4][2];
#pragma unroll
  for (int qc = 0; qc < 4; ++qc)
#pragma unroll
    for (int s = 0; s < 2; ++s)
      qf[qc][s] = *(const short8*)(sPb + s * 2048 + (qc * 16 + col) * 32 + quad * 8);
  __syncthreads();  // sPb now free for P tiles

  floatx4 Oacc[4][4];
#pragma unroll
  for (int mq = 0; mq < 4; ++mq)
#pragma unroll
    for (int nd = 0; nd < 4; ++nd) Oacc[mq][nd] = (floatx4){0.f, 0.f, 0.f, 0.f};
  float lacc[4] = {0.f, 0.f, 0.f, 0.f};
  unsigned short* myP = sPb + wave * 2304;
  unsigned short* vw  = sVb + wave * 2048;

  for (int t = 0; t < 16; ++t) {
    const int buf = t & 1;
    unsigned short* kw = sKb + buf * 8192 + wave * 2048;
    const int ktn = (t + 1) * 128;

    if (t < 15) {
      unsigned short* kd = sKb + (buf ^ 1) * 8192 + wave * 2048;
#pragma unroll
      for (int s = 0; s < 2; ++s)
#pragma unroll
        for (int j = 0; j < 2; ++j)
          async_copy16(Kg + (size_t)(ktn + wave * 32 + j * 16 + l4) * 1024 + s * 32 + lo4,
                       kd + s * 1024 + j * 512 + lane * 8);
      __builtin_amdgcn_s_waitcnt(0xF78);  // vmcnt(8): K(t) drained
    } else {
      __builtin_amdgcn_s_waitcnt(0xF74);  // vmcnt(4): K(15) drained
    }

    floatx4 ST[2][4];
#pragma unroll
    for (int kr = 0; kr < 2; ++kr)
#pragma unroll
      for (int qc = 0; qc < 4; ++qc) ST[kr][qc] = (floatx4){0.f, 0.f, 0.f, 0.f};
#pragma unroll
    for (int s = 0; s < 2; ++s) {
      short8 k0 = *(const short8*)(kw + s * 1024 + col * 32 + quad * 8);
      short8 k1 = *(const short8*)(kw + s * 1024 + (16 + col) * 32 + quad * 8);
#pragma unroll
      for (int qc = 0; qc < 4; ++qc) {
        ST[0][qc] = __builtin_amdgcn_mfma_f32_16x16x32_bf16(k0, qf[qc][s], ST[0][qc], 0, 0, 0);
        ST[1][qc] = __builtin_amdgcn_mfma_f32_16x16x32_bf16(k1, qf[qc][s], ST[1][qc], 0, 0, 0);
      }
    }

#pragma unroll
    for (int kr = 0; kr < 2; ++kr)
#pragma unroll
      for (int qc = 0; qc < 4; ++qc) {
        float p0 = fast_exp2(ST[kr][qc][0]);
        float p1 = fast_exp2(ST[kr][qc][1]);
        float p2 = fast_exp2(ST[kr][qc][2]);
        float p3 = fast_exp2(ST[kr][qc][3]);
        lacc[qc] += (p0 + p1) + (p2 + p3);
        unsigned long long pw =
            ((unsigned long long)f2b_pk(p2, p3) << 32) | f2b_pk(p0, p1);
        *(unsigned long long*)(myP + (qc * 16 + col) * 36 + kr * 16 + quad * 4) = pw;
      }

    short8 pf[4];
#pragma unroll
    for (int mq = 0; mq < 4; ++mq) {
      const unsigned short* pp = myP + (mq * 16 + col) * 36 + quad * 8;
      short4v plo = *(const short4v*)pp;
      short4v phi = *(const short4v*)(pp + 4);
      pf[mq] = (short8){plo[0], plo[1], plo[2], plo[3], phi[0], phi[1], phi[2], phi[3]};
    }

    if (t < 15) __builtin_amdgcn_s_waitcnt(0xF74);  // vmcnt(4): V(t) drained, K(t+1) stays in flight
    else        __builtin_amdgcn_s_waitcnt(0xF70);  // vmcnt(0): V(15) drained

    short8 vf[4];
#pragma unroll
    for (int nd = 0; nd < 4; ++nd)
      vf[nd] = *(const short8*)(vw + (nd * 16 + col) * 32 + quad * 8);
    __builtin_amdgcn_s_waitcnt(0xC07F);  // lgkmcnt(0): vf/pf in registers

    if (t < 15) {
#pragma unroll
      for (int i = 0; i < 4; ++i)
        async_copy16(Vg + (size_t)(i * 16 + l4) * 2048 + ktn + wave * 32 + lo4,
                     vw + i * 512 + lane * 8);
    }

#pragma unroll
    for (int nd = 0; nd < 4; ++nd)
#pragma unroll
      for (int mq = 0; mq < 4; ++mq)
        Oacc[mq][nd] = __builtin_amdgcn_mfma_f32_16x16x32_bf16(pf[mq], vf[nd], Oacc[mq][nd], 0, 0, 0);
  }

  // ---- epilogue: reduce l over quads, O over waves; scale; store
#pragma unroll
  for (int qc = 0; qc < 4; ++qc) {
    lacc[qc] += __shfl_xor(lacc[qc], 16, 64);
    lacc[qc] += __shfl_xor(lacc[qc], 32, 64);
  }
  if (quad == 0) {
#pragma unroll
    for (int qc = 0; qc < 4; ++qc) sL[wave][qc * 16 + col] = lacc[qc];
  }

  float* sO = (float*)sKb;  // 64x64 fp32 = 16KB, aliases buf0 (loop done)
#pragma unroll 1
  for (int ww = 0; ww < 4; ++ww) {
    __syncthreads();
    if (wave == ww) {
#pragma unroll
      for (int mq = 0; mq < 4; ++mq)
#pragma unroll
        for (int nd = 0; nd < 4; ++nd)
#pragma unroll
          for (int r = 0; r < 4; ++r) {
            int idx = (mq * 16 + quad * 4 + r) * 64 + nd * 16 + col;
            if (ww == 0) sO[idx] = Oacc[mq][nd][r];
            else         sO[idx] += Oacc[mq][nd][r];
          }
    }
  }
  __syncthreads();

  {
    int q = tid >> 2, c = tid & 3;
    float l = sL[0][q] + sL[1][q] + sL[2][q] + sL[3][q];
    float inv = 1.f / l;
    const float* row = sO + q * 64 + c * 16;
    unsigned short* dst = CTX + (size_t)(b * 2048 + q0 + q) * 1024 + h * 64 + c * 16;
#pragma unroll
    for (int hf = 0; hf < 2; ++hf) {
      alignas(16) unsigned short ob[8];
#pragma unroll
      for (int j = 0; j < 8; ++j) ob[j] = f2b(row[hf * 8 + j] * inv);
      *(short8*)(dst + hf * 8) = *(const short8*)ob;
    }
  }
}

extern "C" void kernel_launch(void* const* d_in, const int* in_sizes, int n_in,
                              void* d_out, int out_size, void* d_ws, size_t ws_size,
                              hipStream_t stream) {
  const float* x   = (const float*)d_in[0];
  const float* W_q = (const float*)d_in[1];
  const float* b_q = (const float*)d_in[2];
  const float* W_k = (const float*)d_in[3];
  const float* b_k = (const float*)d_in[4];
  const float* W_v = (const float*)d_in[5];
  const float* b_v = (const float*)d_in[6];
  const float* W_o = (const float*)d_in[7];
  const float* b_o = (const float*)d_in[8];
  float* out = (float*)d_out;

  const size_t NX = (size_t)4096 * 1024;
  const size_t NW = (size_t)1024 * 1024;

  unsigned short* p   = (unsigned short*)d_ws;
  unsigned short* xb  = p;  p += NX;
  unsigned short* Wqb = p;  p += NW;
  unsigned short* Wkb = p;  p += NW;
  unsigned short* Wvb = p;  p += NW;
  unsigned short* Wob = p;  p += NW;
  unsigned short* Q   = p;  p += NX;
  unsigned short* Kb  = p;  p += NX;
  unsigned short* VT  = p;  p += NX;  // [32][64][2048]
  unsigned short* CTX = p;  p += NX;

  dim3 blk(256);
  cvt_all_kernel<<<dim3(8192), blk, 0, stream>>>(
      x, W_q, W_k, W_v, W_o, xb, Wqb, Wkb, Wvb, Wob);
  gemm_qkv_kernel<<<dim3(8, 32, 3), blk, 0, stream>>>(
      xb, Wqb, Wkb, Wvb, b_q, b_k, b_v, Q, Kb, VT);
  attention_kernel<<<dim3(32, 32), blk, 0, stream>>>(Q, Kb, VT, CTX);
  gemm_out_kernel<<<dim3(16, 32), blk, 0, stream>>>(CTX, Wob, b_o, out);
}